// Round 1
// baseline (5103.086 us; speedup 1.0000x reference)
//
#include <hip/hip_runtime.h>
#include <hip/hip_bf16.h>
#include <math.h>

// Shapes (fixed): B=8, L=512, D=768, H=12, DK=64, N=B*L=4096, BH=96
// Output layout (floats): context[96*512*768]=37748736 | d[96*512*512]=25165824 | d0[96*512]=49152 | loss[1]
// Scratch plan: Q,K and LL live inside the context output region (fully overwritten at the end).
//               d region holds A until finalize_d converts it in place to d.
//               d_ws only holds tiny arrays (R, m, colsum, diag) ~0.42 MB.

#define INV_SQRT_D 0.03608439182435161f  // 1/sqrt(768)

// ---------------------------------------------------------------------------
// 8x8-per-thread fp32 GEMM micro kernel over a K-chunk of 16.
// At[t][r] (r = output row), Bt[t][c] (c = output col), both row stride 132.
__device__ __forceinline__ void mm_micro(const float* At, const float* Bt,
                                         float acc[8][8], int tx, int ty)
{
#pragma unroll
  for (int t = 0; t < 16; ++t) {
    const float4 a0 = *(const float4*)(At + t*132 + ty*8);
    const float4 a1 = *(const float4*)(At + t*132 + ty*8 + 4);
    const float4 b0 = *(const float4*)(Bt + t*132 + tx*8);
    const float4 b1 = *(const float4*)(Bt + t*132 + tx*8 + 4);
    const float a[8] = {a0.x,a0.y,a0.z,a0.w,a1.x,a1.y,a1.z,a1.w};
    const float b[8] = {b0.x,b0.y,b0.z,b0.w,b1.x,b1.y,b1.z,b1.w};
#pragma unroll
    for (int i = 0; i < 8; ++i)
#pragma unroll
      for (int j = 0; j < 8; ++j)
        acc[i][j] = fmaf(a[i], b[j], acc[i][j]);
  }
}

// ---------------------------------------------------------------------------
// Q = (x@Wq + bq)/sqrt(D), K = x@Wk + bk.   out tiles 128x128, block 256.
__global__ __launch_bounds__(256) void proj_kernel(
    const float* __restrict__ x,
    const float* __restrict__ Wq, const float* __restrict__ bq,
    const float* __restrict__ Wk, const float* __restrict__ bk,
    float* __restrict__ Q, float* __restrict__ Kc)
{
  const float* W; const float* bias; float* out; float scale;
  if (blockIdx.z == 0) { W = Wq; bias = bq; out = Q;  scale = INV_SQRT_D; }
  else                 { W = Wk; bias = bk; out = Kc; scale = 1.0f; }

  __shared__ __align__(16) float At[16*132];
  __shared__ __align__(16) float Bt[16*132];

  const int tx = threadIdx.x, ty = threadIdx.y;
  const int tid = ty*16 + tx;
  const int row0 = blockIdx.y * 128, col0 = blockIdx.x * 128;
  const int lt = tid & 15, lr = tid >> 4;    // A load: t fastest (coalesced 64B)
  const int bc = tid & 127, btr = tid >> 7;  // B load: c fastest (coalesced 512B)

  float acc[8][8] = {};

  for (int kk = 0; kk < 768; kk += 16) {
#pragma unroll
    for (int u = 0; u < 8; ++u) {
      const int r = lr + 16*u;
      At[lt*132 + r] = x[(size_t)(row0 + r)*768 + kk + lt];
    }
#pragma unroll
    for (int u = 0; u < 8; ++u) {
      const int t = btr + 2*u;
      Bt[t*132 + bc] = W[(size_t)(kk + t)*768 + col0 + bc];
    }
    __syncthreads();
    mm_micro(At, Bt, acc, tx, ty);
    __syncthreads();
  }

#pragma unroll
  for (int i = 0; i < 8; ++i) {
    const int r = row0 + ty*8 + i;
#pragma unroll
    for (int j = 0; j < 8; j += 4) {
      const int c = col0 + tx*8 + j;
      float4 v;
      v.x = (acc[i][j+0] + bias[c+0]) * scale;
      v.y = (acc[i][j+1] + bias[c+1]) * scale;
      v.z = (acc[i][j+2] + bias[c+2]) * scale;
      v.w = (acc[i][j+3] + bias[c+3]) * scale;
      *(float4*)(out + (size_t)r*768 + c) = v;
    }
  }
}

// ---------------------------------------------------------------------------
// root = x@Wr + br; m = mask/-10000; R = exp(max(root - m*50, -40)).
__global__ __launch_bounds__(256) void root_kernel(
    const float* __restrict__ x, const float* __restrict__ Wr,
    const float* __restrict__ br, const float* __restrict__ mask,
    float* __restrict__ Rv, float* __restrict__ mv)
{
  const int n = blockIdx.x*4 + (threadIdx.x >> 6);
  const int lane = threadIdx.x & 63;
  float s = 0.0f;
  for (int c = lane; c < 768; c += 64) s += x[(size_t)n*768 + c] * Wr[c];
#pragma unroll
  for (int off = 32; off > 0; off >>= 1) s += __shfl_down(s, off, 64);
  if (lane == 0) {
    const float root = s + br[0];
    const float m = mask[n] * (-1e-4f);
    Rv[n] = expf(fmaxf(root - m*50.0f, -40.0f));
    mv[n] = m;
  }
}

// ---------------------------------------------------------------------------
// A[bh][i][j] = exp(max(q_i . k_j - (m_i+m_j)*50, -40)).  tiles 128x128, K=64.
__global__ __launch_bounds__(256) void scores_kernel(
    const float* __restrict__ Qs, const float* __restrict__ Ks,
    const float* __restrict__ mv, float* __restrict__ A)
{
  const int bh = blockIdx.z, b = bh / 12, h = bh % 12;
  const int i0 = blockIdx.y * 128, j0 = blockIdx.x * 128;
  __shared__ __align__(16) float At[16*132];
  __shared__ __align__(16) float Bt[16*132];
  const int tx = threadIdx.x, ty = threadIdx.y;
  const int tid = ty*16 + tx;
  const int lt = tid & 15, lr = tid >> 4;
  const size_t qbase = (size_t)(b*512 + i0)*768 + h*64;
  const size_t kbase = (size_t)(b*512 + j0)*768 + h*64;

  float acc[8][8] = {};

  for (int kk = 0; kk < 64; kk += 16) {
#pragma unroll
    for (int u = 0; u < 8; ++u) {
      const int r = lr + 16*u;
      At[lt*132 + r] = Qs[qbase + (size_t)r*768 + kk + lt];
      Bt[lt*132 + r] = Ks[kbase + (size_t)r*768 + kk + lt];
    }
    __syncthreads();
    mm_micro(At, Bt, acc, tx, ty);
    __syncthreads();
  }

  float mi[8], mj[8];
#pragma unroll
  for (int i = 0; i < 8; ++i) mi[i] = mv[b*512 + i0 + ty*8 + i];
#pragma unroll
  for (int j = 0; j < 8; ++j) mj[j] = mv[b*512 + j0 + tx*8 + j];

#pragma unroll
  for (int i = 0; i < 8; ++i) {
    const size_t rowb = (size_t)(bh*512 + i0 + ty*8 + i)*512;
#pragma unroll
    for (int j = 0; j < 8; j += 4) {
      float4 v;
      v.x = expf(fmaxf(acc[i][j+0] - (mi[i]+mj[j+0])*50.0f, -40.0f));
      v.y = expf(fmaxf(acc[i][j+1] - (mi[i]+mj[j+1])*50.0f, -40.0f));
      v.z = expf(fmaxf(acc[i][j+2] - (mi[i]+mj[j+2])*50.0f, -40.0f));
      v.w = expf(fmaxf(acc[i][j+3] - (mi[i]+mj[j+3])*50.0f, -40.0f));
      *(float4*)(A + rowb + j0 + tx*8 + j) = v;
    }
  }
}

// ---------------------------------------------------------------------------
// colsum[bh][j] = sum_i A[bh][i][j]
__global__ void colsum_kernel(const float* __restrict__ A, float* __restrict__ colsum)
{
  const int bh = blockIdx.y;
  const int j = blockIdx.x*256 + threadIdx.x;
  const float* Ab = A + (size_t)bh*262144;
  float s = 0.0f;
  for (int i = 0; i < 512; ++i) s += Ab[(size_t)i*512 + j];
  colsum[bh*512 + j] = s;
}

// ---------------------------------------------------------------------------
// M = diag(colsum + R) - A
__global__ void buildM_kernel(const float* __restrict__ A, const float* __restrict__ colsum,
                              const float* __restrict__ Rv, float* __restrict__ M)
{
  const size_t g = ((size_t)blockIdx.x*256 + threadIdx.x)*4;
  const int bh = (int)(g >> 18);
  const int i = (int)((g >> 9) & 511);
  const int j = (int)(g & 511);
  const float4 a = *(const float4*)(A + g);
  float4 v; v.x = -a.x; v.y = -a.y; v.z = -a.z; v.w = -a.w;
  if (i >= j && i < j+4) {
    const float dadd = colsum[bh*512 + i] + Rv[(bh/12)*512 + i];
    ((float*)&v)[i - j] += dadd;
  }
  *(float4*)(M + g) = v;
}

// ---------------------------------------------------------------------------
// In-place blocked Gauss-Jordan inversion (no pivoting; M is column diag-dominant).
// One 1024-thread WG per 512x512 matrix. NB=32 panels, 16 block steps.
// Panel factored in registers; update is W(LDS) x Mp(regs) with float4 global R/W.
__global__ __launch_bounds__(1024) void invert_kernel(float* __restrict__ Mbase)
{
  __shared__ __align__(16) float lds[16384];   // 64 KB, phase-aliased
  float* const fbuf   = lds;        // [512]   (factor phase)
  float* const rowbuf = lds + 512;  // [32]    (factor phase)
  float* const Wl     = lds;        // [512*32] (update phase)

  const int tid  = threadIdx.x;
  const int i    = tid & 511;
  const int half = tid >> 9;
  float* const Mg = Mbase + (size_t)blockIdx.x * 262144;

  const int jcol = (tid & 127) << 2;   // update: 4 cols per thread
  const int ig   = tid >> 7;           // update: row group 0..7 (64 rows each)

  for (int step = 0; step < 16; ++step) {
    const int k0 = step * 32;
    const int cbase = k0 + half*16;

    // ---- load my 16 panel-column entries of row i ----
    float w[16];
    {
      const float* src = Mg + (size_t)i*512 + cbase;
      const float4 t0 = *(const float4*)(src);
      const float4 t1 = *(const float4*)(src+4);
      const float4 t2 = *(const float4*)(src+8);
      const float4 t3 = *(const float4*)(src+12);
      w[0]=t0.x; w[1]=t0.y; w[2]=t0.z;  w[3]=t0.w;
      w[4]=t1.x; w[5]=t1.y; w[6]=t1.z;  w[7]=t1.w;
      w[8]=t2.x; w[9]=t2.y; w[10]=t2.z; w[11]=t2.w;
      w[12]=t3.x;w[13]=t3.y;w[14]=t3.z; w[15]=t3.w;
    }

    // ---- 32 unblocked GJ pivots restricted to panel columns ----
#pragma unroll 1
    for (int kk = 0; kk < 32; ++kk) {
      const int hk = kk >> 4;
      const int ck = kk & 15;
      const int krow = k0 + kk;
      if (half == hk) fbuf[i] = w[ck];
      if (i == krow) {
        float4* rb = (float4*)(rowbuf + half*16);
        rb[0] = make_float4(w[0], w[1], w[2], w[3]);
        rb[1] = make_float4(w[4], w[5], w[6], w[7]);
        rb[2] = make_float4(w[8], w[9], w[10], w[11]);
        rb[3] = make_float4(w[12], w[13], w[14], w[15]);
      }
      __syncthreads();
      const float p = 1.0f / rowbuf[kk];
      const float f = fbuf[i];
      float rv[16];
      {
        const float4* rb = (const float4*)(rowbuf + half*16);
        const float4 r0 = rb[0], r1 = rb[1], r2 = rb[2], r3 = rb[3];
        rv[0]=r0.x; rv[1]=r0.y; rv[2]=r0.z;  rv[3]=r0.w;
        rv[4]=r1.x; rv[5]=r1.y; rv[6]=r1.z;  rv[7]=r1.w;
        rv[8]=r2.x; rv[9]=r2.y; rv[10]=r2.z; rv[11]=r2.w;
        rv[12]=r3.x;rv[13]=r3.y;rv[14]=r3.z; rv[15]=r3.w;
      }
      if (i == krow) {
#pragma unroll
        for (int j = 0; j < 16; ++j)
          w[j] = (half*16 + j == kk) ? p : rv[j]*p;
      } else {
#pragma unroll
        for (int j = 0; j < 16; ++j)
          w[j] = (half*16 + j == kk) ? (-f*p) : fmaf(-f, rv[j]*p, w[j]);
      }
      __syncthreads();
    }

    // ---- dump W to LDS + write panel columns back to global ----
    {
      const float4 v0 = make_float4(w[0], w[1], w[2], w[3]);
      const float4 v1 = make_float4(w[4], w[5], w[6], w[7]);
      const float4 v2 = make_float4(w[8], w[9], w[10], w[11]);
      const float4 v3 = make_float4(w[12], w[13], w[14], w[15]);
      float4* wp = (float4*)(Wl + i*32 + half*16);
      wp[0]=v0; wp[1]=v1; wp[2]=v2; wp[3]=v3;
      float4* gp = (float4*)(Mg + (size_t)i*512 + cbase);
      gp[0]=v0; gp[1]=v1; gp[2]=v2; gp[3]=v3;
    }

    // ---- load OLD panel rows for my 4 columns into registers ----
    float4 mp[32];
#pragma unroll
    for (int kk = 0; kk < 32; ++kk)
      mp[kk] = *(const float4*)(Mg + (size_t)(k0 + kk)*512 + jcol);
    __syncthreads();   // Wl visible; mp loads drained before any update writes

    // ---- rank-32 update of all non-panel columns ----
    if (!(jcol >= k0 && jcol < k0 + 32)) {
#pragma unroll 2
      for (int ii = 0; ii < 64; ++ii) {
        const int irow = ig*64 + ii;
        float* cell = Mg + (size_t)irow*512 + jcol;
        float4 acc;
        if (irow >= k0 && irow < k0 + 32) acc = make_float4(0.f,0.f,0.f,0.f);
        else                              acc = *(const float4*)cell;
        const float* wr = Wl + irow*32;
#pragma unroll
        for (int q = 0; q < 8; ++q) {
          const float4 a4 = *(const float4*)(wr + q*4);
          const float4 m0 = mp[q*4+0], m1 = mp[q*4+1], m2 = mp[q*4+2], m3 = mp[q*4+3];
          acc.x = fmaf(a4.x, m0.x, acc.x); acc.y = fmaf(a4.x, m0.y, acc.y);
          acc.z = fmaf(a4.x, m0.z, acc.z); acc.w = fmaf(a4.x, m0.w, acc.w);
          acc.x = fmaf(a4.y, m1.x, acc.x); acc.y = fmaf(a4.y, m1.y, acc.y);
          acc.z = fmaf(a4.y, m1.z, acc.z); acc.w = fmaf(a4.y, m1.w, acc.w);
          acc.x = fmaf(a4.z, m2.x, acc.x); acc.y = fmaf(a4.z, m2.y, acc.y);
          acc.z = fmaf(a4.z, m2.z, acc.z); acc.w = fmaf(a4.z, m2.w, acc.w);
          acc.x = fmaf(a4.w, m3.x, acc.x); acc.y = fmaf(a4.w, m3.y, acc.y);
          acc.z = fmaf(a4.w, m3.z, acc.z); acc.w = fmaf(a4.w, m3.w, acc.w);
        }
        *(float4*)cell = acc;
      }
    }
    __syncthreads();   // drain before next step's panel load
  }
}

// ---------------------------------------------------------------------------
// diag = diag(LLinv); d0 = R * diag
__global__ void diag_d0_kernel(const float* __restrict__ Minv, const float* __restrict__ Rv,
                               float* __restrict__ diagv, float* __restrict__ d0)
{
  const int bh = blockIdx.x, l = threadIdx.x;
  const float dg = Minv[(size_t)bh*262144 + (size_t)l*513];
  diagv[bh*512 + l] = dg;
  d0[bh*512 + l] = Rv[(bh/12)*512 + l] * dg;
}

// ---------------------------------------------------------------------------
// loss = mean_n( label_n * sum_h -log(clip(d0[b,h,l], 1e-5, 1-1e-5)) )
__global__ __launch_bounds__(1024) void loss_kernel(const float* __restrict__ d0,
                                                    const int* __restrict__ labels,
                                                    float* __restrict__ loss)
{
  float acc = 0.0f;
  for (int n = threadIdx.x; n < 4096; n += 1024) {
    if (labels[n] != 0) {
      const int b = n >> 9, l = n & 511;
      float s = 0.0f;
#pragma unroll
      for (int h = 0; h < 12; ++h) {
        float p = d0[(size_t)(b*12 + h)*512 + l];
        p = fminf(fmaxf(p, 1e-5f), 1.0f - 1e-5f);
        s -= logf(p);
      }
      acc += s;
    }
  }
  __shared__ float red[16];
#pragma unroll
  for (int off = 32; off > 0; off >>= 1) acc += __shfl_down(acc, off, 64);
  const int wv = threadIdx.x >> 6, ln = threadIdx.x & 63;
  if (ln == 0) red[wv] = acc;
  __syncthreads();
  if (threadIdx.x == 0) {
    float t = 0.0f;
    for (int w2 = 0; w2 < 16; ++w2) t += red[w2];
    loss[0] = t * (1.0f/4096.0f);
  }
}

// ---------------------------------------------------------------------------
// d[i][j] = A[i][j] * (diag[j] - LLinv[j][i])   (in place over A)
__global__ __launch_bounds__(256) void finalize_d_kernel(
    float* __restrict__ dmat, const float* __restrict__ Minv, const float* __restrict__ diagv)
{
  const int bh = blockIdx.z;
  const int i0 = blockIdx.y*64, j0 = blockIdx.x*64;
  __shared__ float t[64][65];
  const int tx = threadIdx.x, ty = threadIdx.y;
  const size_t mbase = (size_t)bh*262144;
  for (int jj = ty; jj < 64; jj += 4)
    t[jj][tx] = Minv[mbase + (size_t)(j0+jj)*512 + i0 + tx];
  __syncthreads();
  const float dg_j = diagv[bh*512 + j0 + tx];
  for (int ii = ty; ii < 64; ii += 4) {
    const size_t idx = mbase + (size_t)(i0+ii)*512 + j0 + tx;
    dmat[idx] = dmat[idx] * (dg_j - t[tx][ii]);
  }
}

// ---------------------------------------------------------------------------
// context[b,h,q,:] = sum_k attn[q,k] * x[b,k,:],  attn[q,k] = masked d[k,q]
__global__ __launch_bounds__(256) void context_kernel(
    const float* __restrict__ dmat, const float* __restrict__ x,
    const float* __restrict__ mv, float* __restrict__ ctx)
{
  const int bh = blockIdx.z, b = bh / 12;
  const int q0 = blockIdx.y * 128, c0 = blockIdx.x * 128;
  __shared__ __align__(16) float At[16*132];
  __shared__ __align__(16) float Bt[16*132];
  const int tx = threadIdx.x, ty = threadIdx.y;
  const int tid = ty*16 + tx;
  const int lc = tid & 127, lt2 = tid >> 7;
  const float mq = mv[b*512 + q0 + lc];
  const size_t dbase = (size_t)bh*262144;
  const size_t xbase = (size_t)b*512*768;

  float acc[8][8] = {};

  for (int k0 = 0; k0 < 512; k0 += 16) {
#pragma unroll
    for (int u = 0; u < 8; ++u) {
      const int t = lt2 + 2*u;
      const float mk = mv[b*512 + k0 + t];
      const float dv = dmat[dbase + (size_t)(k0 + t)*512 + q0 + lc];
      At[t*132 + lc] = ((mq + mk) != 0.0f) ? 0.0f : dv;
      Bt[t*132 + lc] = x[xbase + (size_t)(k0 + t)*768 + c0 + lc];
    }
    __syncthreads();
    mm_micro(At, Bt, acc, tx, ty);
    __syncthreads();
  }

#pragma unroll
  for (int i = 0; i < 8; ++i) {
    const size_t rowb = (size_t)(bh*512 + q0 + ty*8 + i)*768;
#pragma unroll
    for (int j = 0; j < 8; j += 4) {
      float4 v;
      v.x = acc[i][j+0]; v.y = acc[i][j+1]; v.z = acc[i][j+2]; v.w = acc[i][j+3];
      *(float4*)(ctx + rowb + c0 + tx*8 + j) = v;
    }
  }
}

// ---------------------------------------------------------------------------
extern "C" void kernel_launch(void* const* d_in, const int* in_sizes, int n_in,
                              void* d_out, int out_size, void* d_ws, size_t ws_size,
                              hipStream_t stream)
{
  (void)in_sizes; (void)n_in; (void)out_size; (void)ws_size;

  const float* x    = (const float*)d_in[0];
  const float* mask = (const float*)d_in[1];
  const int*   roots= (const int*)d_in[2];
  // d_in[3] root_mask: unused by the math
  const float* Wq   = (const float*)d_in[4];
  const float* bq   = (const float*)d_in[5];
  const float* Wk   = (const float*)d_in[6];
  const float* bk   = (const float*)d_in[7];
  const float* Wr   = (const float*)d_in[8];
  const float* br   = (const float*)d_in[9];

  float* out        = (float*)d_out;
  float* ctx_region = out;                 // 37748736 floats
  float* d_region   = out + 37748736;      // 25165824 floats (A -> d in place)
  float* d0_region  = out + 62914560;      // 49152 floats
  float* loss_ptr   = out + 62963712;      // 1 float

  // scratch inside the context region (overwritten by context_kernel at the end)
  float* Qs = ctx_region;                  // 3145728
  float* Ks = ctx_region + 3145728;        // 3145728
  float* Mv = ctx_region + 6291456;        // 25165824 (ends at 31457280 < 37748736)

  float* ws     = (float*)d_ws;
  float* Rv     = ws;                      // 4096
  float* mv     = ws + 4096;               // 4096
  float* colsum = ws + 8192;               // 49152
  float* diagv  = ws + 57344;              // 49152

  proj_kernel   <<<dim3(6,32,2),  dim3(16,16), 0, stream>>>(x, Wq, bq, Wk, bk, Qs, Ks);
  root_kernel   <<<dim3(1024),    dim3(256),   0, stream>>>(x, Wr, br, mask, Rv, mv);
  scores_kernel <<<dim3(4,4,96),  dim3(16,16), 0, stream>>>(Qs, Ks, mv, d_region);
  colsum_kernel <<<dim3(2,96),    dim3(256),   0, stream>>>(d_region, colsum);
  buildM_kernel <<<dim3(24576),   dim3(256),   0, stream>>>(d_region, colsum, Rv, Mv);
  invert_kernel <<<dim3(96),      dim3(1024),  0, stream>>>(Mv);
  diag_d0_kernel<<<dim3(96),      dim3(512),   0, stream>>>(Mv, Rv, diagv, d0_region);
  loss_kernel   <<<dim3(1),       dim3(1024),  0, stream>>>(d0_region, roots, loss_ptr);
  finalize_d_kernel<<<dim3(8,8,96), dim3(64,4), 0, stream>>>(d_region, Mv, diagv);
  context_kernel<<<dim3(6,4,96),  dim3(16,16), 0, stream>>>(d_region, x, mv, ctx_region);
}

// Round 2
// 3581.190 us; speedup vs baseline: 1.4250x; 1.4250x over previous
//
#include <hip/hip_runtime.h>
#include <hip/hip_bf16.h>
#include <math.h>

// Shapes (fixed): B=8, L=512, D=768, H=12, DK=64, N=B*L=4096, BH=96
// Output layout (floats): context[37748736] | d[25165824] | d0[49152] | loss[1]
// Scratch plan: Q,K, LL(Mv), and Mp panel-row scratch live inside the context
// output region (fully overwritten by context_kernel at the end).
// d region holds A until finalize_d converts it in place to d.
// d_ws holds tiny arrays (R, m, colsum, diag) ~0.42 MB.

#define INV_SQRT_D 0.03608439182435161f  // 1/sqrt(768)

// ---------------------------------------------------------------------------
// 8x8-per-thread fp32 GEMM micro kernel over a K-chunk of 16.
// At[t][r] (r = output row), Bt[t][c] (c = output col), both row stride 132.
__device__ __forceinline__ void mm_micro(const float* At, const float* Bt,
                                         float acc[8][8], int tx, int ty)
{
#pragma unroll
  for (int t = 0; t < 16; ++t) {
    const float4 a0 = *(const float4*)(At + t*132 + ty*8);
    const float4 a1 = *(const float4*)(At + t*132 + ty*8 + 4);
    const float4 b0 = *(const float4*)(Bt + t*132 + tx*8);
    const float4 b1 = *(const float4*)(Bt + t*132 + tx*8 + 4);
    const float a[8] = {a0.x,a0.y,a0.z,a0.w,a1.x,a1.y,a1.z,a1.w};
    const float b[8] = {b0.x,b0.y,b0.z,b0.w,b1.x,b1.y,b1.z,b1.w};
#pragma unroll
    for (int i = 0; i < 8; ++i)
#pragma unroll
      for (int j = 0; j < 8; ++j)
        acc[i][j] = fmaf(a[i], b[j], acc[i][j]);
  }
}

// ---------------------------------------------------------------------------
// Q = (x@Wq + bq)/sqrt(D), K = x@Wk + bk.   out tiles 128x128, block 256.
__global__ __launch_bounds__(256) void proj_kernel(
    const float* __restrict__ x,
    const float* __restrict__ Wq, const float* __restrict__ bq,
    const float* __restrict__ Wk, const float* __restrict__ bk,
    float* __restrict__ Q, float* __restrict__ Kc)
{
  const float* W; const float* bias; float* out; float scale;
  if (blockIdx.z == 0) { W = Wq; bias = bq; out = Q;  scale = INV_SQRT_D; }
  else                 { W = Wk; bias = bk; out = Kc; scale = 1.0f; }

  __shared__ __align__(16) float At[16*132];
  __shared__ __align__(16) float Bt[16*132];

  const int tx = threadIdx.x, ty = threadIdx.y;
  const int tid = ty*16 + tx;
  const int row0 = blockIdx.y * 128, col0 = blockIdx.x * 128;
  const int lt = tid & 15, lr = tid >> 4;
  const int bc = tid & 127, btr = tid >> 7;

  float acc[8][8] = {};

  for (int kk = 0; kk < 768; kk += 16) {
#pragma unroll
    for (int u = 0; u < 8; ++u) {
      const int r = lr + 16*u;
      At[lt*132 + r] = x[(size_t)(row0 + r)*768 + kk + lt];
    }
#pragma unroll
    for (int u = 0; u < 8; ++u) {
      const int t = btr + 2*u;
      Bt[t*132 + bc] = W[(size_t)(kk + t)*768 + col0 + bc];
    }
    __syncthreads();
    mm_micro(At, Bt, acc, tx, ty);
    __syncthreads();
  }

#pragma unroll
  for (int i = 0; i < 8; ++i) {
    const int r = row0 + ty*8 + i;
#pragma unroll
    for (int j = 0; j < 8; j += 4) {
      const int c = col0 + tx*8 + j;
      float4 v;
      v.x = (acc[i][j+0] + bias[c+0]) * scale;
      v.y = (acc[i][j+1] + bias[c+1]) * scale;
      v.z = (acc[i][j+2] + bias[c+2]) * scale;
      v.w = (acc[i][j+3] + bias[c+3]) * scale;
      *(float4*)(out + (size_t)r*768 + c) = v;
    }
  }
}

// ---------------------------------------------------------------------------
// root = x@Wr + br; m = mask/-10000; R = exp(max(root - m*50, -40)).
__global__ __launch_bounds__(256) void root_kernel(
    const float* __restrict__ x, const float* __restrict__ Wr,
    const float* __restrict__ br, const float* __restrict__ mask,
    float* __restrict__ Rv, float* __restrict__ mv)
{
  const int n = blockIdx.x*4 + (threadIdx.x >> 6);
  const int lane = threadIdx.x & 63;
  float s = 0.0f;
  for (int c = lane; c < 768; c += 64) s += x[(size_t)n*768 + c] * Wr[c];
#pragma unroll
  for (int off = 32; off > 0; off >>= 1) s += __shfl_down(s, off, 64);
  if (lane == 0) {
    const float root = s + br[0];
    const float m = mask[n] * (-1e-4f);
    Rv[n] = expf(fmaxf(root - m*50.0f, -40.0f));
    mv[n] = m;
  }
}

// ---------------------------------------------------------------------------
// A[bh][i][j] = exp(max(q_i . k_j - (m_i+m_j)*50, -40)).  tiles 128x128, K=64.
__global__ __launch_bounds__(256) void scores_kernel(
    const float* __restrict__ Qs, const float* __restrict__ Ks,
    const float* __restrict__ mv, float* __restrict__ A)
{
  const int bh = blockIdx.z, b = bh / 12, h = bh % 12;
  const int i0 = blockIdx.y * 128, j0 = blockIdx.x * 128;
  __shared__ __align__(16) float At[16*132];
  __shared__ __align__(16) float Bt[16*132];
  const int tx = threadIdx.x, ty = threadIdx.y;
  const int tid = ty*16 + tx;
  const int lt = tid & 15, lr = tid >> 4;
  const size_t qbase = (size_t)(b*512 + i0)*768 + h*64;
  const size_t kbase = (size_t)(b*512 + j0)*768 + h*64;

  float acc[8][8] = {};

  for (int kk = 0; kk < 64; kk += 16) {
#pragma unroll
    for (int u = 0; u < 8; ++u) {
      const int r = lr + 16*u;
      At[lt*132 + r] = Qs[qbase + (size_t)r*768 + kk + lt];
      Bt[lt*132 + r] = Ks[kbase + (size_t)r*768 + kk + lt];
    }
    __syncthreads();
    mm_micro(At, Bt, acc, tx, ty);
    __syncthreads();
  }

  float mi[8], mj[8];
#pragma unroll
  for (int i = 0; i < 8; ++i) mi[i] = mv[b*512 + i0 + ty*8 + i];
#pragma unroll
  for (int j = 0; j < 8; ++j) mj[j] = mv[b*512 + j0 + tx*8 + j];

#pragma unroll
  for (int i = 0; i < 8; ++i) {
    const size_t rowb = (size_t)(bh*512 + i0 + ty*8 + i)*512;
#pragma unroll
    for (int j = 0; j < 8; j += 4) {
      float4 v;
      v.x = expf(fmaxf(acc[i][j+0] - (mi[i]+mj[j+0])*50.0f, -40.0f));
      v.y = expf(fmaxf(acc[i][j+1] - (mi[i]+mj[j+1])*50.0f, -40.0f));
      v.z = expf(fmaxf(acc[i][j+2] - (mi[i]+mj[j+2])*50.0f, -40.0f));
      v.w = expf(fmaxf(acc[i][j+3] - (mi[i]+mj[j+3])*50.0f, -40.0f));
      *(float4*)(A + rowb + j0 + tx*8 + j) = v;
    }
  }
}

// ---------------------------------------------------------------------------
// colsum[bh][j] = sum_i A[bh][i][j]
__global__ void colsum_kernel(const float* __restrict__ A, float* __restrict__ colsum)
{
  const int bh = blockIdx.y;
  const int j = blockIdx.x*256 + threadIdx.x;
  const float* Ab = A + (size_t)bh*262144;
  float s = 0.0f;
  for (int i = 0; i < 512; ++i) s += Ab[(size_t)i*512 + j];
  colsum[bh*512 + j] = s;
}

// ---------------------------------------------------------------------------
// M = diag(colsum + R) - A
__global__ void buildM_kernel(const float* __restrict__ A, const float* __restrict__ colsum,
                              const float* __restrict__ Rv, float* __restrict__ M)
{
  const size_t g = ((size_t)blockIdx.x*256 + threadIdx.x)*4;
  const int bh = (int)(g >> 18);
  const int i = (int)((g >> 9) & 511);
  const int j = (int)(g & 511);
  const float4 a = *(const float4*)(A + g);
  float4 v; v.x = -a.x; v.y = -a.y; v.z = -a.z; v.w = -a.w;
  if (i >= j && i < j+4) {
    const float dadd = colsum[bh*512 + i] + Rv[(bh/12)*512 + i];
    ((float*)&v)[i - j] += dadd;
  }
  *(float4*)(M + g) = v;
}

// ---------------------------------------------------------------------------
// Blocked Gauss-Jordan, NB=64, split per step into panel + update kernels.
// Panel: one 512-thread WG per matrix. (1) copy panel rows (64 x 512) to
// scratch Mp, (2) factor the 512x64 panel (row per thread in VGPRs, pivot row
// broadcast via double-buffered LDS, one barrier per pivot), (3) write W back
// into the panel columns of M.
__global__ __launch_bounds__(512) void gj_panel_kernel(
    float* __restrict__ M, float* __restrict__ Mp, int k0)
{
  float* const Mg  = M  + (size_t)blockIdx.x * 262144;
  float* const Mpg = Mp + (size_t)blockIdx.x * 32768;
  const int tid = threadIdx.x;

  // ---- copy panel rows (old values) to scratch: 16 passes x 512 threads ----
  {
    const int c = (tid & 127) * 4;
    const int rsub = tid >> 7;           // 0..3
#pragma unroll
    for (int p = 0; p < 16; ++p) {
      const int r = p*4 + rsub;          // 0..63
      *(float4*)(Mpg + (size_t)r*512 + c) =
          *(const float4*)(Mg + (size_t)(k0 + r)*512 + c);
    }
  }

  // ---- load my panel row into registers ----
  const int i = tid;                      // one row per thread
  float w[64];
  {
    const float* src = Mg + (size_t)i*512 + k0;
#pragma unroll
    for (int q = 0; q < 16; ++q) {
      const float4 t4 = *(const float4*)(src + q*4);
      w[q*4+0]=t4.x; w[q*4+1]=t4.y; w[q*4+2]=t4.z; w[q*4+3]=t4.w;
    }
  }

  __shared__ __align__(16) float rowbuf[2][64];

#pragma unroll 1
  for (int kk = 0; kk < 64; ++kk) {
    const int b = kk & 1;
    const int krow = k0 + kk;
    if (i == krow) {
      float4* rb = (float4*)rowbuf[b];
#pragma unroll
      for (int q = 0; q < 16; ++q)
        rb[q] = make_float4(w[q*4+0], w[q*4+1], w[q*4+2], w[q*4+3]);
    }
    // f = w[kk] (thread-local, dynamic index -> select chain; overlaps barrier)
    float f = w[0];
#pragma unroll
    for (int j = 1; j < 64; ++j) if (j == kk) f = w[j];
    __syncthreads();
    const float p  = 1.0f / rowbuf[b][kk];
    const float fp = f * p;
    if (i == krow) {
#pragma unroll
      for (int j = 0; j < 64; ++j)
        w[j] = (j == kk) ? p : w[j] * p;
    } else {
#pragma unroll
      for (int j = 0; j < 64; ++j)
        w[j] = (j == kk) ? (-fp) : fmaf(-fp, rowbuf[b][j], w[j]);
    }
    // no second barrier: next pivot writes the OTHER rowbuf buffer
  }

  // ---- write W back into panel columns ----
  {
    float* dst = Mg + (size_t)i*512 + k0;
#pragma unroll
    for (int q = 0; q < 16; ++q)
      *(float4*)(dst + q*4) = make_float4(w[q*4+0], w[q*4+1], w[q*4+2], w[q*4+3]);
  }
}

// Update: M[i][j] = (i in P ? 0 : M_old[i][j]) + W[i][:] . Mp_old[:][j]
// for all j not in P (panel cols hold W, untouched). Full-chip GEMM:
// grid (4,4,96) of 128x128 tiles, K=64 in 4 chunks of 16.
__global__ __launch_bounds__(256) void gj_update_kernel(
    float* __restrict__ M, const float* __restrict__ Mp, int k0)
{
  const int bh = blockIdx.z;
  const int row0 = blockIdx.y * 128, col0 = blockIdx.x * 128;
  float* const Mg = M + (size_t)bh*262144;
  const float* const Mpg = Mp + (size_t)bh*32768;

  __shared__ __align__(16) float At[16*132];
  __shared__ __align__(16) float Bt[16*132];
  const int tx = threadIdx.x, ty = threadIdx.y;
  const int tid = ty*16 + tx;
  const int lt = tid & 15, lr = tid >> 4;
  const int bc = tid & 127, btr = tid >> 7;

  float acc[8][8] = {};

  for (int kc = 0; kc < 64; kc += 16) {
#pragma unroll
    for (int u = 0; u < 8; ++u) {
      const int r = lr + 16*u;
      At[lt*132 + r] = Mg[(size_t)(row0 + r)*512 + k0 + kc + lt];     // W slice
    }
#pragma unroll
    for (int u = 0; u < 8; ++u) {
      const int t = btr + 2*u;
      Bt[t*132 + bc] = Mpg[(size_t)(kc + t)*512 + col0 + bc];         // Mp_old
    }
    __syncthreads();
    mm_micro(At, Bt, acc, tx, ty);
    __syncthreads();
  }

#pragma unroll
  for (int ii = 0; ii < 8; ++ii) {
    const int irow = row0 + ty*8 + ii;
    const bool inP = (irow >= k0) && (irow < k0 + 64);
#pragma unroll
    for (int jj = 0; jj < 8; jj += 4) {
      const int jcol = col0 + tx*8 + jj;
      if (jcol >= k0 && jcol < k0 + 64) continue;   // panel cols hold W
      float* cell = Mg + (size_t)irow*512 + jcol;
      float4 v = make_float4(acc[ii][jj+0], acc[ii][jj+1], acc[ii][jj+2], acc[ii][jj+3]);
      if (!inP) {
        const float4 o = *(const float4*)cell;
        v.x += o.x; v.y += o.y; v.z += o.z; v.w += o.w;
      }
      *(float4*)cell = v;
    }
  }
}

// ---------------------------------------------------------------------------
// diag = diag(LLinv); d0 = R * diag
__global__ void diag_d0_kernel(const float* __restrict__ Minv, const float* __restrict__ Rv,
                               float* __restrict__ diagv, float* __restrict__ d0)
{
  const int bh = blockIdx.x, l = threadIdx.x;
  const float dg = Minv[(size_t)bh*262144 + (size_t)l*513];
  diagv[bh*512 + l] = dg;
  d0[bh*512 + l] = Rv[(bh/12)*512 + l] * dg;
}

// ---------------------------------------------------------------------------
// loss = mean_n( label_n * sum_h -log(clip(d0[b,h,l], 1e-5, 1-1e-5)) )
__global__ __launch_bounds__(1024) void loss_kernel(const float* __restrict__ d0,
                                                    const int* __restrict__ labels,
                                                    float* __restrict__ loss)
{
  float acc = 0.0f;
  for (int n = threadIdx.x; n < 4096; n += 1024) {
    if (labels[n] != 0) {
      const int b = n >> 9, l = n & 511;
      float s = 0.0f;
#pragma unroll
      for (int h = 0; h < 12; ++h) {
        float p = d0[(size_t)(b*12 + h)*512 + l];
        p = fminf(fmaxf(p, 1e-5f), 1.0f - 1e-5f);
        s -= logf(p);
      }
      acc += s;
    }
  }
  __shared__ float red[16];
#pragma unroll
  for (int off = 32; off > 0; off >>= 1) acc += __shfl_down(acc, off, 64);
  const int wv = threadIdx.x >> 6, ln = threadIdx.x & 63;
  if (ln == 0) red[wv] = acc;
  __syncthreads();
  if (threadIdx.x == 0) {
    float t = 0.0f;
    for (int w2 = 0; w2 < 16; ++w2) t += red[w2];
    loss[0] = t * (1.0f/4096.0f);
  }
}

// ---------------------------------------------------------------------------
// d[i][j] = A[i][j] * (diag[j] - LLinv[j][i])   (in place over A)
__global__ __launch_bounds__(256) void finalize_d_kernel(
    float* __restrict__ dmat, const float* __restrict__ Minv, const float* __restrict__ diagv)
{
  const int bh = blockIdx.z;
  const int i0 = blockIdx.y*64, j0 = blockIdx.x*64;
  __shared__ float t[64][65];
  const int tx = threadIdx.x, ty = threadIdx.y;
  const size_t mbase = (size_t)bh*262144;
  for (int jj = ty; jj < 64; jj += 4)
    t[jj][tx] = Minv[mbase + (size_t)(j0+jj)*512 + i0 + tx];
  __syncthreads();
  const float dg_j = diagv[bh*512 + j0 + tx];
  for (int ii = ty; ii < 64; ii += 4) {
    const size_t idx = mbase + (size_t)(i0+ii)*512 + j0 + tx;
    dmat[idx] = dmat[idx] * (dg_j - t[tx][ii]);
  }
}

// ---------------------------------------------------------------------------
// context[b,h,q,:] = sum_k attn[q,k] * x[b,k,:],  attn[q,k] = masked d[k,q]
__global__ __launch_bounds__(256) void context_kernel(
    const float* __restrict__ dmat, const float* __restrict__ x,
    const float* __restrict__ mv, float* __restrict__ ctx)
{
  const int bh = blockIdx.z, b = bh / 12;
  const int q0 = blockIdx.y * 128, c0 = blockIdx.x * 128;
  __shared__ __align__(16) float At[16*132];
  __shared__ __align__(16) float Bt[16*132];
  const int tx = threadIdx.x, ty = threadIdx.y;
  const int tid = ty*16 + tx;
  const int lc = tid & 127, lt2 = tid >> 7;
  const float mq = mv[b*512 + q0 + lc];
  const size_t dbase = (size_t)bh*262144;
  const size_t xbase = (size_t)b*512*768;

  float acc[8][8] = {};

  for (int k0 = 0; k0 < 512; k0 += 16) {
#pragma unroll
    for (int u = 0; u < 8; ++u) {
      const int t = lt2 + 2*u;
      const float mk = mv[b*512 + k0 + t];
      const float dv = dmat[dbase + (size_t)(k0 + t)*512 + q0 + lc];
      At[t*132 + lc] = ((mq + mk) != 0.0f) ? 0.0f : dv;
      Bt[t*132 + lc] = x[xbase + (size_t)(k0 + t)*768 + c0 + lc];
    }
    __syncthreads();
    mm_micro(At, Bt, acc, tx, ty);
    __syncthreads();
  }

#pragma unroll
  for (int i = 0; i < 8; ++i) {
    const size_t rowb = (size_t)(bh*512 + q0 + ty*8 + i)*768;
#pragma unroll
    for (int j = 0; j < 8; j += 4) {
      float4 v;
      v.x = acc[i][j+0]; v.y = acc[i][j+1]; v.z = acc[i][j+2]; v.w = acc[i][j+3];
      *(float4*)(ctx + rowb + c0 + tx*8 + j) = v;
    }
  }
}

// ---------------------------------------------------------------------------
extern "C" void kernel_launch(void* const* d_in, const int* in_sizes, int n_in,
                              void* d_out, int out_size, void* d_ws, size_t ws_size,
                              hipStream_t stream)
{
  (void)in_sizes; (void)n_in; (void)out_size; (void)ws_size;

  const float* x    = (const float*)d_in[0];
  const float* mask = (const float*)d_in[1];
  const int*   roots= (const int*)d_in[2];
  const float* Wq   = (const float*)d_in[4];
  const float* bq   = (const float*)d_in[5];
  const float* Wk   = (const float*)d_in[6];
  const float* bk   = (const float*)d_in[7];
  const float* Wr   = (const float*)d_in[8];
  const float* br   = (const float*)d_in[9];

  float* out        = (float*)d_out;
  float* ctx_region = out;                 // 37748736 floats
  float* d_region   = out + 37748736;      // 25165824 floats (A -> d in place)
  float* d0_region  = out + 62914560;      // 49152 floats
  float* loss_ptr   = out + 62963712;      // 1 float

  // scratch inside the context region (overwritten by context_kernel at the end)
  float* Qs = ctx_region;                  // 3145728
  float* Ks = ctx_region + 3145728;        // 3145728
  float* Mv = ctx_region + 6291456;        // 25165824 (ends at 31457280)
  float* Mp = ctx_region + 31457280;       // 3145728  (ends at 34603008 < 37748736)

  float* ws     = (float*)d_ws;
  float* Rv     = ws;                      // 4096
  float* mv     = ws + 4096;               // 4096
  float* colsum = ws + 8192;               // 49152
  float* diagv  = ws + 57344;              // 49152

  proj_kernel   <<<dim3(6,32,2),  dim3(16,16), 0, stream>>>(x, Wq, bq, Wk, bk, Qs, Ks);
  root_kernel   <<<dim3(1024),    dim3(256),   0, stream>>>(x, Wr, br, mask, Rv, mv);
  scores_kernel <<<dim3(4,4,96),  dim3(16,16), 0, stream>>>(Qs, Ks, mv, d_region);
  colsum_kernel <<<dim3(2,96),    dim3(256),   0, stream>>>(d_region, colsum);
  buildM_kernel <<<dim3(24576),   dim3(256),   0, stream>>>(d_region, colsum, Rv, Mv);

  for (int step = 0; step < 8; ++step) {
    const int k0 = step * 64;
    gj_panel_kernel <<<dim3(96),     dim3(512),   0, stream>>>(Mv, Mp, k0);
    gj_update_kernel<<<dim3(4,4,96), dim3(16,16), 0, stream>>>(Mv, Mp, k0);
  }

  diag_d0_kernel<<<dim3(96),      dim3(512),   0, stream>>>(Mv, Rv, diagv, d0_region);
  loss_kernel   <<<dim3(1),       dim3(1024),  0, stream>>>(d0_region, roots, loss_ptr);
  finalize_d_kernel<<<dim3(8,8,96), dim3(64,4), 0, stream>>>(d_region, Mv, diagv);
  context_kernel<<<dim3(6,4,96),  dim3(16,16), 0, stream>>>(d_region, x, mv, ctx_region);
}